// Round 1
// baseline (120.154 us; speedup 1.0000x reference)
//
#include <hip/hip_runtime.h>

// Problem constants (match reference)
constexpr int B  = 16384;
constexpr int D  = 64;
constexpr int LA = 20;
constexpr int LC = 5;

__device__ __forceinline__ float waveReduceSum(float v) {
    #pragma unroll
    for (int off = 32; off >= 1; off >>= 1)
        v += __shfl_xor(v, off, 64);
    return v;
}

// One wave (64 lanes) per batch row; lane == feature dim.
__global__ __launch_bounds__(256, 4) void aspect_kernel(
    const int*   __restrict__ user_id,
    const int*   __restrict__ artists_id,
    const int*   __restrict__ categories_id,
    const float* __restrict__ user_factors,
    const float* __restrict__ entity_factors,
    const float* __restrict__ relation_k,
    float*       __restrict__ out)
{
    const int lane = threadIdx.x & 63;
    const int wid  = threadIdx.x >> 6;
    const int b    = (blockIdx.x << 2) + wid;   // 4 waves / block
    if (b >= B) return;

    // Output layout: prediction(B) | scores(B*3) | c_act(B) | c_dir(B) | niubi_act(B*LA) | niubi_dir(B*LC)
    float* pred    = out;
    float* scores  = out + B;
    float* c_act_o = out + B + 3 * B;
    float* c_dir_o = out + B + 4 * B;
    float* niubiA  = out + B + 5 * B;
    float* niubiC  = niubiA + (size_t)B * LA;

    const int   uid = user_id[b];
    const float u   = user_factors[(size_t)uid * D + lane];

    // users @ relation_k  (relation_k is (D, 3) row-major)
    float p0 = u * relation_k[lane * 3 + 0];
    float p1 = u * relation_k[lane * 3 + 1];
    float p2 = u * relation_k[lane * 3 + 2];
    #pragma unroll
    for (int off = 32; off >= 1; off >>= 1) {
        p0 += __shfl_xor(p0, off, 64);
        p1 += __shfl_xor(p1, off, 64);
        p2 += __shfl_xor(p2, off, 64);
    }
    // leaky_relu(slope 0.2) + softmax over 3
    p0 = p0 >= 0.f ? p0 : 0.2f * p0;
    p1 = p1 >= 0.f ? p1 : 0.2f * p1;
    p2 = p2 >= 0.f ? p2 : 0.2f * p2;
    const float m   = fmaxf(p0, fmaxf(p1, p2));
    const float e0  = expf(p0 - m), e1 = expf(p1 - m), e2 = expf(p2 - m);
    const float inv = 1.f / (e0 + e1 + e2);
    const float s0 = e0 * inv, s1 = e1 * inv, s2 = e2 * inv;

    // artists contribution
    float sumA = 0.f, nvA = 0.f;
    #pragma unroll
    for (int l = 0; l < LA; ++l) {
        const int idx = artists_id[b * LA + l];
        const float pre = waveReduceSum(entity_factors[(size_t)idx * D + lane] * u);
        sumA += pre;
        if (lane == l) nvA = pre;   // stash for coalesced store
    }
    const float c_act = sumA * (1.f / LA);

    // categories contribution
    float sumC = 0.f, nvC = 0.f;
    #pragma unroll
    for (int l = 0; l < LC; ++l) {
        const int idx = categories_id[b * LC + l];
        const float pre = waveReduceSum(entity_factors[(size_t)idx * D + lane] * u);
        sumC += pre;
        if (lane == l) nvC = pre;
    }
    const float c_dir = sumC * (1.f / LC);

    // Coalesced-ish predicated stores
    if (lane < LA) niubiA[(size_t)b * LA + lane] = nvA;
    if (lane < LC) niubiC[(size_t)b * LC + lane] = nvC;
    if (lane < 3)  scores[b * 3 + lane] = (lane == 0) ? s0 : (lane == 1 ? s1 : s2);
    if (lane == 0) {
        pred[b]    = (c_act * s0 + c_dir * s1) / (s0 + s1);
        c_act_o[b] = c_act;
        c_dir_o[b] = c_dir;
    }
}

extern "C" void kernel_launch(void* const* d_in, const int* in_sizes, int n_in,
                              void* d_out, int out_size, void* d_ws, size_t ws_size,
                              hipStream_t stream) {
    const int*   user_id        = (const int*)d_in[0];
    const int*   artists_id     = (const int*)d_in[1];
    const int*   categories_id  = (const int*)d_in[2];
    // d_in[3] = rate (unused scalar)
    const float* user_factors   = (const float*)d_in[4];
    const float* entity_factors = (const float*)d_in[5];
    const float* relation_k     = (const float*)d_in[6];
    float*       out            = (float*)d_out;

    const int waves_per_block = 4;
    const int grid = B / waves_per_block;   // 4096
    aspect_kernel<<<grid, 64 * waves_per_block, 0, stream>>>(
        user_id, artists_id, categories_id, user_factors, entity_factors, relation_k, out);
}

// Round 3
// 104.883 us; speedup vs baseline: 1.1456x; 1.1456x over previous
//
#include <hip/hip_runtime.h>

constexpr int B  = 16384;
constexpr int D  = 64;
constexpr int LA = 20;
constexpr int LC = 5;

// ds_swizzle xor pattern: (xor_mask<<10) | 0x1F  (BitMode, and=0x1F, or=0)
template <int PAT>
__device__ __forceinline__ float swz(float v) {
    return __int_as_float(__builtin_amdgcn_ds_swizzle(__float_as_int(v), PAT));
}

// Reduce N independent values across a 16-lane group, stage-interleaved for ILP.
// All xor masks < 16, so ds_swizzle (32-lane domain) is valid; result is
// broadcast to all 16 lanes of the group.
template <int N>
__device__ __forceinline__ void reduce16(float (&p)[N]) {
    #pragma unroll
    for (int l = 0; l < N; ++l) p[l] += swz<0x201F>(p[l]);  // xor 8
    #pragma unroll
    for (int l = 0; l < N; ++l) p[l] += swz<0x101F>(p[l]);  // xor 4
    #pragma unroll
    for (int l = 0; l < N; ++l) p[l] += swz<0x081F>(p[l]);  // xor 2
    #pragma unroll
    for (int l = 0; l < N; ++l) p[l] += swz<0x041F>(p[l]);  // xor 1
}

// 16 lanes per batch row, each lane holds 4 dims (float4). 16 rows per block.
__global__ __launch_bounds__(256, 4) void aspect_kernel(
    const int*   __restrict__ user_id,
    const int*   __restrict__ artists_id,
    const int*   __restrict__ categories_id,
    const float* __restrict__ user_factors,
    const float* __restrict__ entity_factors,
    const float* __restrict__ relation_k,
    float*       __restrict__ out)
{
    const int tid = threadIdx.x;
    const int sl  = tid & 15;        // sub-lane within 16-lane group
    const int grp = tid >> 4;        // group index within block (0..15)
    const int b   = (blockIdx.x << 4) + grp;   // 1024 blocks * 16 rows == B

    // Output layout: prediction(B) | scores(B*3) | c_act(B) | c_dir(B) | niubi_act(B*LA) | niubi_dir(B*LC)
    float* pred    = out;
    float* scores  = out + B;
    float* c_act_o = out + (size_t)4 * B;
    float* c_dir_o = out + (size_t)5 * B;
    float* niubiA  = out + (size_t)6 * B;
    float* niubiC  = niubiA + (size_t)B * LA;

    const int    uid = user_id[b];
    const float4 u4  = *(const float4*)&user_factors[(size_t)uid * D + sl * 4];

    // ---- users @ relation_k (D x 3), leaky_relu, softmax over 3 ----
    float ps[3] = {0.f, 0.f, 0.f};
    {
        const int d0 = sl * 4;
        ps[0] = fmaf(u4.x, relation_k[(d0+0)*3+0], fmaf(u4.y, relation_k[(d0+1)*3+0],
                fmaf(u4.z, relation_k[(d0+2)*3+0], u4.w * relation_k[(d0+3)*3+0])));
        ps[1] = fmaf(u4.x, relation_k[(d0+0)*3+1], fmaf(u4.y, relation_k[(d0+1)*3+1],
                fmaf(u4.z, relation_k[(d0+2)*3+1], u4.w * relation_k[(d0+3)*3+1])));
        ps[2] = fmaf(u4.x, relation_k[(d0+0)*3+2], fmaf(u4.y, relation_k[(d0+1)*3+2],
                fmaf(u4.z, relation_k[(d0+2)*3+2], u4.w * relation_k[(d0+3)*3+2])));
    }
    reduce16(ps);
    float q0 = ps[0] >= 0.f ? ps[0] : 0.2f * ps[0];
    float q1 = ps[1] >= 0.f ? ps[1] : 0.2f * ps[1];
    float q2 = ps[2] >= 0.f ? ps[2] : 0.2f * ps[2];
    const float m   = fmaxf(q0, fmaxf(q1, q2));
    const float e0  = __expf(q0 - m), e1 = __expf(q1 - m), e2 = __expf(q2 - m);
    const float inv = 1.f / (e0 + e1 + e2);
    const float s0 = e0 * inv, s1 = e1 * inv, s2 = e2 * inv;

    // ---- artists: 20 gathered dot products ----
    float pa[LA];
    #pragma unroll
    for (int l = 0; l < LA; ++l) {
        const int    idx = artists_id[b * LA + l];
        const float4 e   = *(const float4*)&entity_factors[(size_t)idx * D + sl * 4];
        pa[l] = fmaf(e.x, u4.x, fmaf(e.y, u4.y, fmaf(e.z, u4.z, e.w * u4.w)));
    }
    reduce16(pa);
    float sumA = 0.f;
    #pragma unroll
    for (int l = 0; l < LA; ++l) sumA += pa[l];
    const float c_act = sumA * (1.f / LA);

    // ---- categories: 5 gathered dot products ----
    float pc[LC];
    #pragma unroll
    for (int l = 0; l < LC; ++l) {
        const int    idx = categories_id[b * LC + l];
        const float4 e   = *(const float4*)&entity_factors[(size_t)idx * D + sl * 4];
        pc[l] = fmaf(e.x, u4.x, fmaf(e.y, u4.y, fmaf(e.z, u4.z, e.w * u4.w)));
    }
    reduce16(pc);
    float sumC = 0.f;
    #pragma unroll
    for (int l = 0; l < LC; ++l) sumC += pc[l];
    const float c_dir = sumC * (1.f / LC);

    // ---- stores (all lanes in group hold all reduced values) ----
    // niubi_act: 80B/row, 16B-aligned; lanes 0..4 each store one float4 (branchless select)
    if (sl < 5) {
        float4 v;
        v.x = sl == 0 ? pa[0] : sl == 1 ? pa[4]  : sl == 2 ? pa[8]  : sl == 3 ? pa[12] : pa[16];
        v.y = sl == 0 ? pa[1] : sl == 1 ? pa[5]  : sl == 2 ? pa[9]  : sl == 3 ? pa[13] : pa[17];
        v.z = sl == 0 ? pa[2] : sl == 1 ? pa[6]  : sl == 2 ? pa[10] : sl == 3 ? pa[14] : pa[18];
        v.w = sl == 0 ? pa[3] : sl == 1 ? pa[7]  : sl == 2 ? pa[11] : sl == 3 ? pa[15] : pa[19];
        *(float4*)&niubiA[(size_t)b * LA + sl * 4] = v;
    }
    // niubi_dir: 5 scalars per row
    if (sl < LC) {
        const float v = sl == 0 ? pc[0] : sl == 1 ? pc[1] : sl == 2 ? pc[2] : sl == 3 ? pc[3] : pc[4];
        niubiC[(size_t)b * LC + sl] = v;
    }
    if (sl < 3) {
        const float v = sl == 0 ? s0 : sl == 1 ? s1 : s2;
        scores[b * 3 + sl] = v;
    }
    if (sl == 0) {
        pred[b]    = (c_act * s0 + c_dir * s1) / (s0 + s1);
        c_act_o[b] = c_act;
        c_dir_o[b] = c_dir;
    }
}

extern "C" void kernel_launch(void* const* d_in, const int* in_sizes, int n_in,
                              void* d_out, int out_size, void* d_ws, size_t ws_size,
                              hipStream_t stream) {
    const int*   user_id        = (const int*)d_in[0];
    const int*   artists_id     = (const int*)d_in[1];
    const int*   categories_id  = (const int*)d_in[2];
    // d_in[3] = rate (unused scalar)
    const float* user_factors   = (const float*)d_in[4];
    const float* entity_factors = (const float*)d_in[5];
    const float* relation_k     = (const float*)d_in[6];
    float*       out            = (float*)d_out;

    const int rows_per_block = 16;               // 16 groups of 16 lanes = 256 threads
    const int grid = B / rows_per_block;         // 1024
    aspect_kernel<<<grid, 256, 0, stream>>>(
        user_id, artists_id, categories_id, user_factors, entity_factors, relation_k, out);
}

// Round 4
// 104.003 us; speedup vs baseline: 1.1553x; 1.0085x over previous
//
#include <hip/hip_runtime.h>

constexpr int B  = 16384;
constexpr int D  = 64;
constexpr int LA = 20;
constexpr int LC = 5;

// DPP row-rotate-and-add: v += rotate_right_within_16lane_row(v, N).
// CTRL: 0x120+N = row_ror:N (row = 16 lanes on CDNA).
template <int CTRL>
__device__ __forceinline__ float ror_add(float v) {
    const int r = __builtin_amdgcn_update_dpp(
        0, __float_as_int(v), CTRL, 0xF, 0xF, true);
    return v + __int_as_float(r);
}

// Reduce N independent values across a 16-lane row, stage-interleaved for ILP.
// After 4 rotate stages (8,4,2,1) every lane of the row holds the full sum.
// Pure VALU (no LDS pipe, no lgkmcnt waits).
template <int N>
__device__ __forceinline__ void reduce16(float (&p)[N]) {
    #pragma unroll
    for (int l = 0; l < N; ++l) p[l] = ror_add<0x128>(p[l]);  // ror 8
    #pragma unroll
    for (int l = 0; l < N; ++l) p[l] = ror_add<0x124>(p[l]);  // ror 4
    #pragma unroll
    for (int l = 0; l < N; ++l) p[l] = ror_add<0x122>(p[l]);  // ror 2
    #pragma unroll
    for (int l = 0; l < N; ++l) p[l] = ror_add<0x121>(p[l]);  // ror 1
}

// 16 lanes per batch row, each lane holds 4 dims (float4). 16 rows per block.
__global__ __launch_bounds__(256, 4) void aspect_kernel(
    const int*   __restrict__ user_id,
    const int*   __restrict__ artists_id,
    const int*   __restrict__ categories_id,
    const float* __restrict__ user_factors,
    const float* __restrict__ entity_factors,
    const float* __restrict__ relation_k,
    float*       __restrict__ out)
{
    const int tid = threadIdx.x;
    const int sl  = tid & 15;        // sub-lane within 16-lane group (DPP row)
    const int grp = tid >> 4;        // group index within block (0..15)
    const int b   = (blockIdx.x << 4) + grp;   // 1024 blocks * 16 rows == B

    // Output layout: prediction(B) | scores(B*3) | c_act(B) | c_dir(B) | niubi_act(B*LA) | niubi_dir(B*LC)
    float* pred    = out;
    float* scores  = out + B;
    float* c_act_o = out + (size_t)4 * B;
    float* c_dir_o = out + (size_t)5 * B;
    float* niubiA  = out + (size_t)6 * B;
    float* niubiC  = niubiA + (size_t)B * LA;

    const int    uid = user_id[b];
    const float4 u4  = *(const float4*)&user_factors[(size_t)uid * D + sl * 4];

    // ---- users @ relation_k (D x 3), leaky_relu, softmax over 3 ----
    float ps[3];
    {
        const int d0 = sl * 4;
        ps[0] = fmaf(u4.x, relation_k[(d0+0)*3+0], fmaf(u4.y, relation_k[(d0+1)*3+0],
                fmaf(u4.z, relation_k[(d0+2)*3+0], u4.w * relation_k[(d0+3)*3+0])));
        ps[1] = fmaf(u4.x, relation_k[(d0+0)*3+1], fmaf(u4.y, relation_k[(d0+1)*3+1],
                fmaf(u4.z, relation_k[(d0+2)*3+1], u4.w * relation_k[(d0+3)*3+1])));
        ps[2] = fmaf(u4.x, relation_k[(d0+0)*3+2], fmaf(u4.y, relation_k[(d0+1)*3+2],
                fmaf(u4.z, relation_k[(d0+2)*3+2], u4.w * relation_k[(d0+3)*3+2])));
    }
    reduce16(ps);
    float q0 = ps[0] >= 0.f ? ps[0] : 0.2f * ps[0];
    float q1 = ps[1] >= 0.f ? ps[1] : 0.2f * ps[1];
    float q2 = ps[2] >= 0.f ? ps[2] : 0.2f * ps[2];
    const float m   = fmaxf(q0, fmaxf(q1, q2));
    const float e0  = __expf(q0 - m), e1 = __expf(q1 - m), e2 = __expf(q2 - m);
    const float inv = 1.f / (e0 + e1 + e2);
    const float s0 = e0 * inv, s1 = e1 * inv, s2 = e2 * inv;

    // ---- artists: 20 gathered dot products ----
    float pa[LA];
    #pragma unroll
    for (int l = 0; l < LA; ++l) {
        const int    idx = artists_id[b * LA + l];
        const float4 e   = *(const float4*)&entity_factors[(size_t)idx * D + sl * 4];
        pa[l] = fmaf(e.x, u4.x, fmaf(e.y, u4.y, fmaf(e.z, u4.z, e.w * u4.w)));
    }
    reduce16(pa);
    float sumA = 0.f;
    #pragma unroll
    for (int l = 0; l < LA; ++l) sumA += pa[l];
    const float c_act = sumA * (1.f / LA);

    // ---- categories: 5 gathered dot products ----
    float pc[LC];
    #pragma unroll
    for (int l = 0; l < LC; ++l) {
        const int    idx = categories_id[b * LC + l];
        const float4 e   = *(const float4*)&entity_factors[(size_t)idx * D + sl * 4];
        pc[l] = fmaf(e.x, u4.x, fmaf(e.y, u4.y, fmaf(e.z, u4.z, e.w * u4.w)));
    }
    reduce16(pc);
    float sumC = 0.f;
    #pragma unroll
    for (int l = 0; l < LC; ++l) sumC += pc[l];
    const float c_dir = sumC * (1.f / LC);

    // ---- stores (all lanes in group hold all reduced values) ----
    // niubi_act: 80B/row, 16B-aligned; lanes 0..4 each store one float4 (branchless select)
    if (sl < 5) {
        float4 v;
        v.x = sl == 0 ? pa[0] : sl == 1 ? pa[4]  : sl == 2 ? pa[8]  : sl == 3 ? pa[12] : pa[16];
        v.y = sl == 0 ? pa[1] : sl == 1 ? pa[5]  : sl == 2 ? pa[9]  : sl == 3 ? pa[13] : pa[17];
        v.z = sl == 0 ? pa[2] : sl == 1 ? pa[6]  : sl == 2 ? pa[10] : sl == 3 ? pa[14] : pa[18];
        v.w = sl == 0 ? pa[3] : sl == 1 ? pa[7]  : sl == 2 ? pa[11] : sl == 3 ? pa[15] : pa[19];
        *(float4*)&niubiA[(size_t)b * LA + sl * 4] = v;
    }
    // niubi_dir: 5 scalars per row
    if (sl < LC) {
        const float v = sl == 0 ? pc[0] : sl == 1 ? pc[1] : sl == 2 ? pc[2] : sl == 3 ? pc[3] : pc[4];
        niubiC[(size_t)b * LC + sl] = v;
    }
    if (sl < 3) {
        const float v = sl == 0 ? s0 : sl == 1 ? s1 : s2;
        scores[b * 3 + sl] = v;
    }
    if (sl == 0) {
        pred[b]    = (c_act * s0 + c_dir * s1) / (s0 + s1);
        c_act_o[b] = c_act;
        c_dir_o[b] = c_dir;
    }
}

extern "C" void kernel_launch(void* const* d_in, const int* in_sizes, int n_in,
                              void* d_out, int out_size, void* d_ws, size_t ws_size,
                              hipStream_t stream) {
    const int*   user_id        = (const int*)d_in[0];
    const int*   artists_id     = (const int*)d_in[1];
    const int*   categories_id  = (const int*)d_in[2];
    // d_in[3] = rate (unused scalar)
    const float* user_factors   = (const float*)d_in[4];
    const float* entity_factors = (const float*)d_in[5];
    const float* relation_k     = (const float*)d_in[6];
    float*       out            = (float*)d_out;

    const int rows_per_block = 16;               // 16 groups of 16 lanes = 256 threads
    const int grid = B / rows_per_block;         // 1024
    aspect_kernel<<<grid, 256, 0, stream>>>(
        user_id, artists_id, categories_id, user_factors, entity_factors, relation_k, out);
}